// Round 1
// baseline (160.989 us; speedup 1.0000x reference)
//
#include <hip/hip_runtime.h>
#include <math.h>

#define DD 256

// Branchless erf, Abramowitz-Stegun 7.1.26 (max abs err 1.5e-7).
// Uses raw v_rcp_f32 / v_exp_f32 (exp2) transcendentals.
__device__ __forceinline__ float fast_erf(float x) {
    float ax = __builtin_fabsf(x);
    float t  = __builtin_amdgcn_rcpf(__builtin_fmaf(0.3275911f, ax, 1.0f));
    float e  = __builtin_amdgcn_exp2f(x * x * -1.4426950408889634f); // exp(-x^2)
    float p  = __builtin_fmaf(1.061405429f, t, -1.453152027f);
    p = __builtin_fmaf(p, t, 1.421413741f);
    p = __builtin_fmaf(p, t, -0.284496736f);
    p = __builtin_fmaf(p, t, 0.254829592f);
    float y = __builtin_fmaf(-p * t, e, 1.0f); // 1 - poly(t)*t*exp(-x^2)
    return __builtin_copysignf(y, x);
}

__global__ __launch_bounds__(DD) void kd_layernorm_kernel(
        const float* __restrict__ x,
        const float* __restrict__ w,
        const float* __restrict__ b,
        float* __restrict__ out) {
    __shared__ float sxs[DD];     // row values pre-scaled by 1/(bw*sqrt2)
    __shared__ float sred[8];     // per-wave partial sums: [0..3]=sum, [4..7]=sumsq
    __shared__ float sscale;

    const int row = blockIdx.x;
    const int j   = threadIdx.x;
    const float xj = x[(size_t)row * DD + j];

    // Block reduction for sum and sum-of-squares (4 waves of 64).
    float s = xj, q = xj * xj;
    #pragma unroll
    for (int off = 32; off >= 1; off >>= 1) {
        s += __shfl_down(s, off, 64);
        q += __shfl_down(q, off, 64);
    }
    if ((j & 63) == 0) { sred[j >> 6] = s; sred[4 + (j >> 6)] = q; }
    __syncthreads();
    if (j == 0) {
        float S = sred[0] + sred[1] + sred[2] + sred[3];
        float Q = sred[4] + sred[5] + sred[6] + sred[7];
        // ddof=1 variance
        float var = (Q - S * S * (1.0f / DD)) * (1.0f / (DD - 1));
        // Silverman: bw = 0.9 * std * D^(-1/5);  D=256 -> 256^-0.2
        float bw = 0.9f * __builtin_sqrtf(var) * 0.32987697769322355f;
        sscale = 1.0f / (bw * 1.41421356237309505f); // 1/(bw*sqrt(2))
    }
    __syncthreads();
    const float scale = sscale;
    const float xjs = xj * scale;
    sxs[j] = xjs;
    __syncthreads();

    // 2*cdf - 1 = (1/D) * sum_k erf((x_j - x_k)/(bw*sqrt2))
    float acc = 0.0f;
    #pragma unroll 8
    for (int k = 0; k < DD; ++k) {
        acc += fast_erf(xjs - sxs[k]);
    }
    float y = acc * (1.0f / DD);
    float normed = erfinvf(y) * 1.41421356237309505f; // sqrt(2)*erfinv
    out[(size_t)row * DD + j] = __builtin_fmaf(normed, w[j], b[j]);
}

extern "C" void kernel_launch(void* const* d_in, const int* in_sizes, int n_in,
                              void* d_out, int out_size, void* d_ws, size_t ws_size,
                              hipStream_t stream) {
    const float* x = (const float*)d_in[0];
    const float* w = (const float*)d_in[1];
    const float* b = (const float*)d_in[2];
    float* out = (float*)d_out;
    const int nrows = in_sizes[0] / DD;
    kd_layernorm_kernel<<<nrows, DD, 0, stream>>>(x, w, b, out);
}

// Round 2
// 145.168 us; speedup vs baseline: 1.1090x; 1.1090x over previous
//
#include <hip/hip_runtime.h>
#include <math.h>

#define DD 256
#define NW 4  // rows (waves) per block

// Branchless erf, Abramowitz-Stegun 7.1.26 (max abs err 1.5e-7).
__device__ __forceinline__ float fast_erf(float x) {
    float ax = __builtin_fabsf(x);
    float t  = __builtin_amdgcn_rcpf(__builtin_fmaf(0.3275911f, ax, 1.0f));
    float e  = __builtin_amdgcn_exp2f(x * x * -1.4426950408889634f); // exp(-x^2)
    float p  = __builtin_fmaf(1.061405429f, t, -1.453152027f);
    p = __builtin_fmaf(p, t, 1.421413741f);
    p = __builtin_fmaf(p, t, -0.284496736f);
    p = __builtin_fmaf(p, t, 0.254829592f);
    float y = __builtin_fmaf(-p * t, e, 1.0f);
    return __builtin_copysignf(y, x);
}

__device__ __forceinline__ float bperm(int byte_addr, float v) {
    return __int_as_float(__builtin_amdgcn_ds_bpermute(byte_addr, __float_as_int(v)));
}

// One wave per row. Lane l holds elements {l, 64+l, 128+l, 192+l}.
// Antisymmetry: erf(u_j - u_k) = -erf(u_k - u_j), so each unordered pair is
// evaluated once; the negated value is routed to the partner lane's
// accumulator with a single ds_bpermute per (rotation, partner-reg) since all
// 4 contributions to acc[b] at lane l+r originate from the same lane l.
__global__ __launch_bounds__(64 * NW) void kd_layernorm_kernel(
        const float* __restrict__ x,
        const float* __restrict__ w,
        const float* __restrict__ bia,
        float* __restrict__ out) {
    const int lane = threadIdx.x & 63;
    const int wid  = threadIdx.x >> 6;
    const int row  = blockIdx.x * NW + wid;
    const float* xr = x + (size_t)row * DD;

    float u[4];
    #pragma unroll
    for (int a = 0; a < 4; ++a) u[a] = xr[a * 64 + lane];

    // Wave-wide sum / sumsq via xor butterfly (all lanes end with totals).
    float s = (u[0] + u[1]) + (u[2] + u[3]);
    float q = __builtin_fmaf(u[0], u[0], u[1] * u[1]) +
              __builtin_fmaf(u[2], u[2], u[3] * u[3]);
    #pragma unroll
    for (int off = 32; off >= 1; off >>= 1) {
        s += __shfl_xor(s, off, 64);
        q += __shfl_xor(q, off, 64);
    }
    float var = (q - s * s * (1.0f / DD)) * (1.0f / (DD - 1)); // ddof=1
    float bw = 0.9f * __builtin_sqrtf(var) * 0.32987697769322355f; // * 256^-0.2
    float scale = 1.0f / (bw * 1.41421356237309505f);              // 1/(bw*sqrt2)
    #pragma unroll
    for (int a = 0; a < 4; ++a) u[a] *= scale;

    float acc[4] = {0.f, 0.f, 0.f, 0.f};

    // r = 0: intra-lane pairs (6 erf)
    {
        float e01 = fast_erf(u[0] - u[1]);
        float e02 = fast_erf(u[0] - u[2]);
        float e03 = fast_erf(u[0] - u[3]);
        float e12 = fast_erf(u[1] - u[2]);
        float e13 = fast_erf(u[1] - u[3]);
        float e23 = fast_erf(u[2] - u[3]);
        acc[0] += (e01 + e02) + e03;
        acc[1] += (e12 + e13) - e01;
        acc[2] += (e23 - e02) - e12;
        acc[3] -= (e03 + e13) + e23;
    }

    const int lb = lane << 2;
    // r = 1..31: plus path for rotation +r, minus path covers rotation 64-r.
    #pragma unroll 2
    for (int r = 1; r < 32; ++r) {
        const int ap = (lb + (r << 2)) & 255;
        const int am = (lb - (r << 2)) & 255;
        float v0 = bperm(ap, u[0]);
        float v1 = bperm(ap, u[1]);
        float v2 = bperm(ap, u[2]);
        float v3 = bperm(ap, u[3]);
        float es0, es1, es2, es3;
        {
            float e0 = fast_erf(u[0] - v0), e1 = fast_erf(u[1] - v0);
            float e2 = fast_erf(u[2] - v0), e3 = fast_erf(u[3] - v0);
            acc[0] += e0; acc[1] += e1; acc[2] += e2; acc[3] += e3;
            es0 = (e0 + e1) + (e2 + e3);
        }
        {
            float e0 = fast_erf(u[0] - v1), e1 = fast_erf(u[1] - v1);
            float e2 = fast_erf(u[2] - v1), e3 = fast_erf(u[3] - v1);
            acc[0] += e0; acc[1] += e1; acc[2] += e2; acc[3] += e3;
            es1 = (e0 + e1) + (e2 + e3);
        }
        {
            float e0 = fast_erf(u[0] - v2), e1 = fast_erf(u[1] - v2);
            float e2 = fast_erf(u[2] - v2), e3 = fast_erf(u[3] - v2);
            acc[0] += e0; acc[1] += e1; acc[2] += e2; acc[3] += e3;
            es2 = (e0 + e1) + (e2 + e3);
        }
        {
            float e0 = fast_erf(u[0] - v3), e1 = fast_erf(u[1] - v3);
            float e2 = fast_erf(u[2] - v3), e3 = fast_erf(u[3] - v3);
            acc[0] += e0; acc[1] += e1; acc[2] += e2; acc[3] += e3;
            es3 = (e0 + e1) + (e2 + e3);
        }
        // route negated pair values to partner-lane accumulators
        acc[0] -= bperm(am, es0);
        acc[1] -= bperm(am, es1);
        acc[2] -= bperm(am, es2);
        acc[3] -= bperm(am, es3);
    }

    // r = 32: each ordered pair computed directly by its owner lane (16 erf)
    {
        const int ap = (lb + 128) & 255;
        float v0 = bperm(ap, u[0]);
        float v1 = bperm(ap, u[1]);
        float v2 = bperm(ap, u[2]);
        float v3 = bperm(ap, u[3]);
        #pragma unroll
        for (int a = 0; a < 4; ++a) {
            acc[a] += fast_erf(u[a] - v0) + fast_erf(u[a] - v1) +
                      fast_erf(u[a] - v2) + fast_erf(u[a] - v3);
        }
    }

    // Epilogue: y = mean erf -> PPF -> scale/shift
    #pragma unroll
    for (int a = 0; a < 4; ++a) {
        float y = acc[a] * (1.0f / DD);
        float normed = erfinvf(y) * 1.41421356237309505f;
        int idx = a * 64 + lane;
        out[(size_t)row * DD + idx] =
            __builtin_fmaf(normed, w[idx], bia[idx]);
    }
}

extern "C" void kernel_launch(void* const* d_in, const int* in_sizes, int n_in,
                              void* d_out, int out_size, void* d_ws, size_t ws_size,
                              hipStream_t stream) {
    const float* x = (const float*)d_in[0];
    const float* w = (const float*)d_in[1];
    const float* b = (const float*)d_in[2];
    float* out = (float*)d_out;
    const int nrows = in_sizes[0] / DD;
    kd_layernorm_kernel<<<nrows / NW, 64 * NW, 0, stream>>>(x, w, b, out);
}

// Round 3
// 110.743 us; speedup vs baseline: 1.4537x; 1.3109x over previous
//
#include <hip/hip_runtime.h>
#include <math.h>

#define DD 256
#define NW 4  // rows (waves) per block

// Branchless erf, Abramowitz-Stegun 7.1.26 (max abs err 1.5e-7).
__device__ __forceinline__ float fast_erf(float x) {
    float ax = __builtin_fabsf(x);
    float t  = __builtin_amdgcn_rcpf(__builtin_fmaf(0.3275911f, ax, 1.0f));
    float e  = __builtin_amdgcn_exp2f(x * x * -1.4426950408889634f); // exp(-x^2)
    float p  = __builtin_fmaf(1.061405429f, t, -1.453152027f);
    p = __builtin_fmaf(p, t, 1.421413741f);
    p = __builtin_fmaf(p, t, -0.284496736f);
    p = __builtin_fmaf(p, t, 0.254829592f);
    float y = __builtin_fmaf(-p * t, e, 1.0f);
    return __builtin_copysignf(y, x);
}

__device__ __forceinline__ float bperm(int byte_addr, float v) {
    return __int_as_float(__builtin_amdgcn_ds_bpermute(byte_addr, __float_as_int(v)));
}

// One wave per row. Lane l holds elements {l, 64+l, 128+l, 192+l}.
// Antisymmetry: erf(u_j - u_k) = -erf(u_k - u_j): each unordered pair is
// evaluated once; negated values are routed to the partner lane via one
// ds_bpermute per (rotation, partner-reg).
// __launch_bounds__(256,4): 4 waves/EU minimum -> <=128 VGPRs, so all 4
// available waves/SIMD are resident (R2's 252-VGPR schedule ran ~1 wave/SIMD
// and stalled on the erf dep chain at VALUBusy=63%).
__global__ __launch_bounds__(64 * NW, 4) void kd_layernorm_kernel(
        const float* __restrict__ x,
        const float* __restrict__ w,
        const float* __restrict__ bia,
        float* __restrict__ out) {
    const int lane = threadIdx.x & 63;
    const int wid  = threadIdx.x >> 6;
    const int row  = blockIdx.x * NW + wid;
    const float* xr = x + (size_t)row * DD;

    float u[4];
    #pragma unroll
    for (int a = 0; a < 4; ++a) u[a] = xr[a * 64 + lane];

    // Wave-wide sum / sumsq via xor butterfly (all lanes end with totals).
    float s = (u[0] + u[1]) + (u[2] + u[3]);
    float q = __builtin_fmaf(u[0], u[0], u[1] * u[1]) +
              __builtin_fmaf(u[2], u[2], u[3] * u[3]);
    #pragma unroll
    for (int off = 32; off >= 1; off >>= 1) {
        s += __shfl_xor(s, off, 64);
        q += __shfl_xor(q, off, 64);
    }
    float var = (q - s * s * (1.0f / DD)) * (1.0f / (DD - 1)); // ddof=1
    float bw = 0.9f * __builtin_sqrtf(var) * 0.32987697769322355f; // * 256^-0.2
    float scale = 1.0f / (bw * 1.41421356237309505f);              // 1/(bw*sqrt2)
    #pragma unroll
    for (int a = 0; a < 4; ++a) u[a] *= scale;

    float acc[4] = {0.f, 0.f, 0.f, 0.f};

    // r = 0: intra-lane pairs (6 erf)
    {
        float e01 = fast_erf(u[0] - u[1]);
        float e02 = fast_erf(u[0] - u[2]);
        float e03 = fast_erf(u[0] - u[3]);
        float e12 = fast_erf(u[1] - u[2]);
        float e13 = fast_erf(u[1] - u[3]);
        float e23 = fast_erf(u[2] - u[3]);
        acc[0] += (e01 + e02) + e03;
        acc[1] += (e12 + e13) - e01;
        acc[2] += (e23 - e02) - e12;
        acc[3] -= (e03 + e13) + e23;
    }

    const int lb = lane << 2;
    // r = 1..31: plus path for rotation +r, minus path covers rotation 64-r.
    // unroll_count(1): R2 let the scheduler pipeline 2 iterations -> 252 VGPRs.
    #pragma clang loop unroll_count(1)
    for (int r = 1; r < 32; ++r) {
        const int ap = (lb + (r << 2)) & 255;
        const int am = (lb - (r << 2)) & 255;
        float v0 = bperm(ap, u[0]);
        float v1 = bperm(ap, u[1]);
        float v2 = bperm(ap, u[2]);
        float v3 = bperm(ap, u[3]);
        float es0, es1, es2, es3;
        {
            float e0 = fast_erf(u[0] - v0), e1 = fast_erf(u[1] - v0);
            float e2 = fast_erf(u[2] - v0), e3 = fast_erf(u[3] - v0);
            acc[0] += e0; acc[1] += e1; acc[2] += e2; acc[3] += e3;
            es0 = (e0 + e1) + (e2 + e3);
        }
        {
            float e0 = fast_erf(u[0] - v1), e1 = fast_erf(u[1] - v1);
            float e2 = fast_erf(u[2] - v1), e3 = fast_erf(u[3] - v1);
            acc[0] += e0; acc[1] += e1; acc[2] += e2; acc[3] += e3;
            es1 = (e0 + e1) + (e2 + e3);
        }
        {
            float e0 = fast_erf(u[0] - v2), e1 = fast_erf(u[1] - v2);
            float e2 = fast_erf(u[2] - v2), e3 = fast_erf(u[3] - v2);
            acc[0] += e0; acc[1] += e1; acc[2] += e2; acc[3] += e3;
            es2 = (e0 + e1) + (e2 + e3);
        }
        {
            float e0 = fast_erf(u[0] - v3), e1 = fast_erf(u[1] - v3);
            float e2 = fast_erf(u[2] - v3), e3 = fast_erf(u[3] - v3);
            acc[0] += e0; acc[1] += e1; acc[2] += e2; acc[3] += e3;
            es3 = (e0 + e1) + (e2 + e3);
        }
        // route negated pair values to partner-lane accumulators
        acc[0] -= bperm(am, es0);
        acc[1] -= bperm(am, es1);
        acc[2] -= bperm(am, es2);
        acc[3] -= bperm(am, es3);
    }

    // r = 32: each ordered pair computed directly by its owner lane (16 erf)
    {
        const int ap = (lb + 128) & 255;
        float v0 = bperm(ap, u[0]);
        float v1 = bperm(ap, u[1]);
        float v2 = bperm(ap, u[2]);
        float v3 = bperm(ap, u[3]);
        #pragma unroll
        for (int a = 0; a < 4; ++a) {
            acc[a] += fast_erf(u[a] - v0) + fast_erf(u[a] - v1) +
                      fast_erf(u[a] - v2) + fast_erf(u[a] - v3);
        }
    }

    // Epilogue: y = mean erf -> PPF -> scale/shift
    #pragma unroll
    for (int a = 0; a < 4; ++a) {
        float y = acc[a] * (1.0f / DD);
        float normed = erfinvf(y) * 1.41421356237309505f;
        int idx = a * 64 + lane;
        out[(size_t)row * DD + idx] =
            __builtin_fmaf(normed, w[idx], bia[idx]);
    }
}

extern "C" void kernel_launch(void* const* d_in, const int* in_sizes, int n_in,
                              void* d_out, int out_size, void* d_ws, size_t ws_size,
                              hipStream_t stream) {
    const float* x = (const float*)d_in[0];
    const float* w = (const float*)d_in[1];
    const float* b = (const float*)d_in[2];
    float* out = (float*)d_out;
    const int nrows = in_sizes[0] / DD;
    kd_layernorm_kernel<<<nrows / NW, 64 * NW, 0, stream>>>(x, w, b, out);
}

// Round 4
// 107.118 us; speedup vs baseline: 1.5029x; 1.0338x over previous
//
#include <hip/hip_runtime.h>
#include <math.h>

#define DD 256
#define NW 4  // rows (waves) per block

typedef float v2f __attribute__((ext_vector_type(2)));

__device__ __forceinline__ float bperm(int byte_addr, float v) {
    return __int_as_float(__builtin_amdgcn_ds_bpermute(byte_addr, __float_as_int(v)));
}

// Packed-pair erf, Abramowitz-Stegun 7.1.26 (max abs err 1.5e-7).
// float2 arithmetic lowers to v_pk_fma_f32 / v_pk_add_f32 on gfx90a+ (2 fp32
// lanes per issue); rcp/exp are quarter-rate transcendentals, scalar only.
__device__ __forceinline__ v2f fast_erf2(v2f x) {
    v2f ax; ax.x = __builtin_fabsf(x.x); ax.y = __builtin_fabsf(x.y);
    const v2f c0327 = {0.3275911f, 0.3275911f};
    const v2f one   = {1.0f, 1.0f};
    v2f targ = __builtin_elementwise_fma(c0327, ax, one);
    v2f t; t.x = __builtin_amdgcn_rcpf(targ.x); t.y = __builtin_amdgcn_rcpf(targ.y);
    const v2f nl2e = {-1.4426950408889634f, -1.4426950408889634f};
    v2f ea = (x * x) * nl2e;
    v2f e; e.x = __builtin_amdgcn_exp2f(ea.x); e.y = __builtin_amdgcn_exp2f(ea.y);
    const v2f k4 = { 1.061405429f,  1.061405429f};
    const v2f k3 = {-1.453152027f, -1.453152027f};
    const v2f k2 = { 1.421413741f,  1.421413741f};
    const v2f k1 = {-0.284496736f, -0.284496736f};
    const v2f k0 = { 0.254829592f,  0.254829592f};
    v2f p = __builtin_elementwise_fma(k4, t, k3);
    p = __builtin_elementwise_fma(p, t, k2);
    p = __builtin_elementwise_fma(p, t, k1);
    p = __builtin_elementwise_fma(p, t, k0);
    v2f y = __builtin_elementwise_fma(-(p * t), e, one);
    v2f r; r.x = __builtin_copysignf(y.x, x.x); r.y = __builtin_copysignf(y.y, x.y);
    return r;
}

// One wave per row. Lane l holds elements {l, 64+l, 128+l, 192+l} as
// U01=(u0,u1), U23=(u2,u3). Antisymmetry: each unordered pair evaluated once,
// negation routed to partner lane via ds_bpermute. Both DS round-trips are
// software-prefetched: rotation r+1's partner values are fetched before
// rotation r's erf block, and the routed subtraction is deferred one
// iteration (pending regs p0..p3), so DS latency hides under ~500 cyc of
// packed VALU even at the grid-limited 4 waves/SIMD.
__global__ __launch_bounds__(64 * NW, 4) void kd_layernorm_kernel(
        const float* __restrict__ x,
        const float* __restrict__ w,
        const float* __restrict__ bia,
        float* __restrict__ out) {
    const int lane = threadIdx.x & 63;
    const int wid  = threadIdx.x >> 6;
    const int row  = blockIdx.x * NW + wid;
    const float* xr = x + (size_t)row * DD;

    float u0 = xr[lane], u1 = xr[64 + lane], u2 = xr[128 + lane], u3 = xr[192 + lane];

    // Wave-wide sum / sumsq via xor butterfly.
    float s = (u0 + u1) + (u2 + u3);
    float q = __builtin_fmaf(u0, u0, u1 * u1) + __builtin_fmaf(u2, u2, u3 * u3);
    #pragma unroll
    for (int off = 32; off >= 1; off >>= 1) {
        s += __shfl_xor(s, off, 64);
        q += __shfl_xor(q, off, 64);
    }
    float var = (q - s * s * (1.0f / DD)) * (1.0f / (DD - 1)); // ddof=1
    float bw = 0.9f * __builtin_sqrtf(var) * 0.32987697769322355f; // * 256^-0.2
    float scale = 1.0f / (bw * 1.41421356237309505f);              // 1/(bw*sqrt2)
    u0 *= scale; u1 *= scale; u2 *= scale; u3 *= scale;

    v2f U01 = {u0, u1}, U23 = {u2, u3};
    v2f A01 = {0.f, 0.f}, A23 = {0.f, 0.f};

    // r = 0: intra-lane pairs (6 erf, 3 packed calls)
    {
        v2f Da = {u0 - u1, u0 - u2};
        v2f Db = {u0 - u3, u1 - u2};
        v2f Dc = {u1 - u3, u2 - u3};
        v2f Ea = fast_erf2(Da), Eb = fast_erf2(Db), Ec = fast_erf2(Dc);
        v2f i01 = {(Ea.x + Ea.y) + Eb.x, (Eb.y + Ec.x) - Ea.x};
        v2f i23 = {(Ec.y - Ea.y) - Eb.y, -((Eb.x + Ec.x) + Ec.y)};
        A01 += i01; A23 += i23;
    }

    const int lb = lane << 2;
    // preload rotation r=1 partner values
    int ap = (lb + 4) & 255;
    float c0 = bperm(ap, u0), c1 = bperm(ap, u1), c2 = bperm(ap, u2), c3 = bperm(ap, u3);
    float p0 = 0.f, p1 = 0.f, p2 = 0.f, p3 = 0.f;

    #pragma clang loop unroll_count(1)
    for (int r = 1; r <= 31; ++r) {
        // prefetch rotation r+1 (r=31 fetches rotation 32, used after loop)
        const int apn = (lb + ((r + 1) << 2)) & 255;
        float n0 = bperm(apn, u0), n1 = bperm(apn, u1),
              n2 = bperm(apn, u2), n3 = bperm(apn, u3);

        float es0, es1, es2, es3;
        {
            v2f V = {c0, c0};
            v2f E01 = fast_erf2(U01 - V), E23 = fast_erf2(U23 - V);
            A01 += E01; A23 += E23;
            v2f Es = E01 + E23; es0 = Es.x + Es.y;
        }
        {
            v2f V = {c1, c1};
            v2f E01 = fast_erf2(U01 - V), E23 = fast_erf2(U23 - V);
            A01 += E01; A23 += E23;
            v2f Es = E01 + E23; es1 = Es.x + Es.y;
        }
        {
            v2f V = {c2, c2};
            v2f E01 = fast_erf2(U01 - V), E23 = fast_erf2(U23 - V);
            A01 += E01; A23 += E23;
            v2f Es = E01 + E23; es2 = Es.x + Es.y;
        }
        {
            v2f V = {c3, c3};
            v2f E01 = fast_erf2(U01 - V), E23 = fast_erf2(U23 - V);
            A01 += E01; A23 += E23;
            v2f Es = E01 + E23; es3 = Es.x + Es.y;
        }

        // deferred routed subtraction from rotation r-1 (zeros on r=1)
        v2f P01 = {p0, p1}, P23 = {p2, p3};
        A01 -= P01; A23 -= P23;

        const int am = (lb - (r << 2)) & 255;
        p0 = bperm(am, es0); p1 = bperm(am, es1);
        p2 = bperm(am, es2); p3 = bperm(am, es3);

        c0 = n0; c1 = n1; c2 = n2; c3 = n3;
    }
    {
        v2f P01 = {p0, p1}, P23 = {p2, p3};
        A01 -= P01; A23 -= P23;
    }

    // r = 32: c holds rotation-32 partners; each ordered pair computed by its
    // owner lane (16 erf, 8 packed calls)
    {
        v2f V0 = {c0, c0}, V1 = {c1, c1}, V2 = {c2, c2}, V3 = {c3, c3};
        A01 += fast_erf2(U01 - V0); A23 += fast_erf2(U23 - V0);
        A01 += fast_erf2(U01 - V1); A23 += fast_erf2(U23 - V1);
        A01 += fast_erf2(U01 - V2); A23 += fast_erf2(U23 - V2);
        A01 += fast_erf2(U01 - V3); A23 += fast_erf2(U23 - V3);
    }

    // Epilogue: y = mean erf -> PPF -> scale/shift
    float accv[4] = {A01.x, A01.y, A23.x, A23.y};
    #pragma unroll
    for (int a = 0; a < 4; ++a) {
        float y = accv[a] * (1.0f / DD);
        float normed = erfinvf(y) * 1.41421356237309505f;
        int idx = a * 64 + lane;
        out[(size_t)row * DD + idx] = __builtin_fmaf(normed, w[idx], bia[idx]);
    }
}

extern "C" void kernel_launch(void* const* d_in, const int* in_sizes, int n_in,
                              void* d_out, int out_size, void* d_ws, size_t ws_size,
                              hipStream_t stream) {
    const float* x = (const float*)d_in[0];
    const float* w = (const float*)d_in[1];
    const float* b = (const float*)d_in[2];
    float* out = (float*)d_out;
    const int nrows = in_sizes[0] / DD;
    kd_layernorm_kernel<<<nrows / NW, 64 * NW, 0, stream>>>(x, w, b, out);
}

// Round 6
// 80.373 us; speedup vs baseline: 2.0030x; 1.3328x over previous
//
#include <hip/hip_runtime.h>
#include <math.h>

#define DD 256
#define NW 4          // rows (waves) per block
#define MFREQ 60      // Fourier modes: omega_M = 2*pi*60/84 = 4.49, e^{-w^2/2}=4e-5
#define LPER 84.0f    // period: wrap-safe while row (max-min)/bw <= 36 (~10.7 sigma)

typedef float v2f __attribute__((ext_vector_type(2)));

// x + dpp_shifted(x); old=0 so invalid source lanes contribute 0.
// dpp ctrl must be an ICE -> template parameter.
template <int CTRL>
__device__ __forceinline__ float dpp_add(float x) {
    return x + __int_as_float(__builtin_amdgcn_update_dpp(
        0, __float_as_int(x), CTRL, 0xf, 0xf, false));
}
// Full 64-lane sum (rocPRIM pattern): row_shr 1,2,4,8 -> each 16-row's lane15
// has the row sum; row_bcast15/31 fold rows; lane 63 has the total; broadcast
// via readlane. 7 full-rate VALU ops, no LDS, no barrier.
__device__ __forceinline__ float wave_sum(float x) {
    x = dpp_add<0x111>(x); // row_shr:1
    x = dpp_add<0x112>(x); // row_shr:2
    x = dpp_add<0x114>(x); // row_shr:4
    x = dpp_add<0x118>(x); // row_shr:8
    x = dpp_add<0x142>(x); // row_bcast:15
    x = dpp_add<0x143>(x); // row_bcast:31
    return __int_as_float(__builtin_amdgcn_readlane(__float_as_int(x), 63));
}

// Poisson-summation KDE-CDF: Phi(d) = 0.5 + d/L + sum_m gamma_m sin(w_m d),
// w_m = 2 pi m / L, gamma_m = e^{-w_m^2/2}/(pi m). The pairwise mean over k
// separates: sum_k sin(w_m(v_j-v_k)) = s_mj*C_m - c_mj*S_m with row sums
// C_m = sum_k cos(w_m v_k), S_m = sum_k sin(w_m v_k). O(D*M) instead of O(D^2).
__global__ __launch_bounds__(64 * NW, 4) void kd_layernorm_kernel(
        const float* __restrict__ x,
        const float* __restrict__ w,
        const float* __restrict__ bia,
        float* __restrict__ out) {
    const int lane = threadIdx.x & 63;
    const int wid  = threadIdx.x >> 6;
    const int row  = blockIdx.x * NW + wid;
    const float* xr = x + (size_t)row * DD;

    float u0 = xr[lane], u1 = xr[64 + lane], u2 = xr[128 + lane], u3 = xr[192 + lane];

    float ssum = wave_sum((u0 + u1) + (u2 + u3));
    float qsum = wave_sum(__builtin_fmaf(u0, u0, u1 * u1) +
                          __builtin_fmaf(u2, u2, u3 * u3));
    float var = (qsum - ssum * ssum * (1.0f / DD)) * (1.0f / (DD - 1)); // ddof=1
    float bw = 0.9f * __builtin_sqrtf(var) * 0.32987697769322355f;      // *256^-0.2
    float scale = 1.0f / bw;                                            // v = x/bw
    float v0 = u0 * scale, v1 = u1 * scale, v2 = u2 * scale, v3 = u3 * scale;
    float meanv = ssum * scale * (1.0f / DD);

    const float w1 = 6.28318530717958648f / LPER;
    v2f s1a = {__sinf(w1 * v0), __sinf(w1 * v1)};
    v2f s1b = {__sinf(w1 * v2), __sinf(w1 * v3)};
    v2f c1a = {__cosf(w1 * v0), __cosf(w1 * v1)};
    v2f c1b = {__cosf(w1 * v2), __cosf(w1 * v3)};

    v2f sma = s1a, smb = s1b, cma = c1a, cmb = c1b;   // m = 1 state
    v2f Ra = {0.f, 0.f}, Rb = {0.f, 0.f};

    // g_m = e^{-m^2 w1^2/2} by multiplicative recurrence (exact constants
    // computed by device expf once; drift over 60 steps ~1e-5 relative).
    float g   = __expf(-0.5f * w1 * w1);
    float rr  = __expf(-1.5f * w1 * w1);
    const float rho = __expf(-w1 * w1);
    float fm = 1.0f;

    #pragma clang loop unroll_count(1)
    for (int m = 1; m <= MFREQ; ++m) {
        // row sums C_m, S_m (this lane holds 4 of the 256 elements)
        v2f sp = sma + smb;
        v2f cp = cma + cmb;
        float Stot = wave_sum(sp.x + sp.y);
        float Ctot = wave_sum(cp.x + cp.y);
        float sc = g * 0.31830988618f * __builtin_amdgcn_rcpf(fm); // gamma_m
        float gC = Ctot * sc, gS = Stot * sc;
        v2f vgC = {gC, gC}, vgS = {gS, gS};
        Ra = __builtin_elementwise_fma(sma, vgC, Ra);
        Ra = __builtin_elementwise_fma(cma, -vgS, Ra);
        Rb = __builtin_elementwise_fma(smb, vgC, Rb);
        Rb = __builtin_elementwise_fma(cmb, -vgS, Rb);
        // angle-addition recurrence to m+1
        v2f nsa = __builtin_elementwise_fma(sma, c1a, cma * s1a);
        v2f nca = __builtin_elementwise_fma(cma, c1a, -(sma * s1a));
        v2f nsb = __builtin_elementwise_fma(smb, c1b, cmb * s1b);
        v2f ncb = __builtin_elementwise_fma(cmb, c1b, -(smb * s1b));
        sma = nsa; cma = nca; smb = nsb; cmb = ncb;
        g *= rr; rr *= rho; fm += 1.0f;
    }

    // y = 2*cdf - 1 = 2*[(v_j - mean_v)/L + R_j/256]
    float vv[4] = {v0, v1, v2, v3};
    float Rv[4] = {Ra.x, Ra.y, Rb.x, Rb.y};
    #pragma unroll
    for (int a = 0; a < 4; ++a) {
        float y = 2.0f * ((vv[a] - meanv) * (1.0f / LPER) + Rv[a] * (1.0f / DD));
        float normed = erfinvf(y) * 1.41421356237309505f;
        int idx = a * 64 + lane;
        out[(size_t)row * DD + idx] = __builtin_fmaf(normed, w[idx], bia[idx]);
    }
}

extern "C" void kernel_launch(void* const* d_in, const int* in_sizes, int n_in,
                              void* d_out, int out_size, void* d_ws, size_t ws_size,
                              hipStream_t stream) {
    const float* x = (const float*)d_in[0];
    const float* w = (const float*)d_in[1];
    const float* b = (const float*)d_in[2];
    float* out = (float*)d_out;
    const int nrows = in_sizes[0] / DD;
    kd_layernorm_kernel<<<nrows / NW, 64 * NW, 0, stream>>>(x, w, b, out);
}

// Round 7
// 67.563 us; speedup vs baseline: 2.3828x; 1.1896x over previous
//
#include <hip/hip_runtime.h>
#include <math.h>

#define DD 256
#define NW 4  // rows (waves) per block

typedef float v2f __attribute__((ext_vector_type(2)));

// ---- DPP wave-64 reductions (rocPRIM pattern), no LDS, no barrier ----
template <int CTRL>
__device__ __forceinline__ float dpp_add(float x) {
    return x + __int_as_float(__builtin_amdgcn_update_dpp(
        0, __float_as_int(x), CTRL, 0xf, 0xf, false));
}
template <int CTRL>
__device__ __forceinline__ float dpp_mov_self(float x) {
    // old = x: invalid source lanes yield x (identity for max/min)
    return __int_as_float(__builtin_amdgcn_update_dpp(
        __float_as_int(x), __float_as_int(x), CTRL, 0xf, 0xf, false));
}
__device__ __forceinline__ float wave_sum(float x) {
    x = dpp_add<0x111>(x); x = dpp_add<0x112>(x);
    x = dpp_add<0x114>(x); x = dpp_add<0x118>(x);
    x = dpp_add<0x142>(x); x = dpp_add<0x143>(x);
    return __int_as_float(__builtin_amdgcn_readlane(__float_as_int(x), 63));
}
__device__ __forceinline__ float wave_max(float x) {
    x = __builtin_fmaxf(x, dpp_mov_self<0x111>(x));
    x = __builtin_fmaxf(x, dpp_mov_self<0x112>(x));
    x = __builtin_fmaxf(x, dpp_mov_self<0x114>(x));
    x = __builtin_fmaxf(x, dpp_mov_self<0x118>(x));
    x = __builtin_fmaxf(x, dpp_mov_self<0x142>(x));
    x = __builtin_fmaxf(x, dpp_mov_self<0x143>(x));
    return __int_as_float(__builtin_amdgcn_readlane(__float_as_int(x), 63));
}
__device__ __forceinline__ float wave_min(float x) {
    x = __builtin_fminf(x, dpp_mov_self<0x111>(x));
    x = __builtin_fminf(x, dpp_mov_self<0x112>(x));
    x = __builtin_fminf(x, dpp_mov_self<0x114>(x));
    x = __builtin_fminf(x, dpp_mov_self<0x118>(x));
    x = __builtin_fminf(x, dpp_mov_self<0x142>(x));
    x = __builtin_fminf(x, dpp_mov_self<0x143>(x));
    return __int_as_float(__builtin_amdgcn_readlane(__float_as_int(x), 63));
}

// Giles' erfinv, central branch only (valid: |y| <= 1-1/256 => w <= 4.86 < 5).
// Branchless: 1 v_log_f32 + 10 FMA. Returns sqrt(2)*erfinv(y).
__device__ __forceinline__ float ppf_from_y(float y) {
    float omy2 = __builtin_fmaf(-y, y, 1.0f);
    // w = -ln(1-y^2) - 2.5  via v_log_f32 (log2)
    float wg = __builtin_fmaf(-__builtin_amdgcn_logf(omy2), 0.69314718056f, -2.5f);
    float p = 2.81022636e-08f;
    p = __builtin_fmaf(p, wg, 3.43273939e-07f);
    p = __builtin_fmaf(p, wg, -3.5233877e-06f);
    p = __builtin_fmaf(p, wg, -4.39150654e-06f);
    p = __builtin_fmaf(p, wg, 0.00021858087f);
    p = __builtin_fmaf(p, wg, -0.00125372503f);
    p = __builtin_fmaf(p, wg, -0.00417768164f);
    p = __builtin_fmaf(p, wg, 0.246640727f);
    p = __builtin_fmaf(p, wg, 1.50140941f);
    return p * y * 1.41421356237309505f;
}

// Poisson-summation KDE-CDF (validated R6): Phi(d) = 0.5 + d/L + sum_m
// gamma_m sin(w_m d), w_m = 2 pi m / L, gamma_m = e^{-w_m^2/2}/(pi m).
// Pairwise mean separates via row sums C_m = sum_k cos(w_m v_k),
// S_m = sum_k sin(w_m v_k).  O(D*M) with adaptive per-row L and M:
// L = range_v + 10 (periodization error Phi(-10) ~ 8e-24), truncation at
// omega_max = 4.4 => M = ceil(0.70*L) ~ 20 typical (was fixed 60).
__global__ __launch_bounds__(64 * NW, 4) void kd_layernorm_kernel(
        const float* __restrict__ x,
        const float* __restrict__ wgt,
        const float* __restrict__ bia,
        float* __restrict__ out) {
    const int lane = threadIdx.x & 63;
    const int wid  = threadIdx.x >> 6;
    const int row  = blockIdx.x * NW + wid;
    const float* xr = x + (size_t)row * DD;

    float u0 = xr[lane], u1 = xr[64 + lane], u2 = xr[128 + lane], u3 = xr[192 + lane];

    float ssum = wave_sum((u0 + u1) + (u2 + u3));
    float qsum = wave_sum(__builtin_fmaf(u0, u0, u1 * u1) +
                          __builtin_fmaf(u2, u2, u3 * u3));
    float xmax = wave_max(__builtin_fmaxf(__builtin_fmaxf(u0, u1),
                                          __builtin_fmaxf(u2, u3)));
    float xmin = wave_min(__builtin_fminf(__builtin_fminf(u0, u1),
                                          __builtin_fminf(u2, u3)));

    float var = (qsum - ssum * ssum * (1.0f / DD)) * (1.0f / (DD - 1)); // ddof=1
    float bw = 0.9f * __builtin_sqrtf(var) * 0.32987697769322355f;      // *256^-0.2
    float invbw = __builtin_amdgcn_rcpf(bw);
    float v0 = u0 * invbw, v1 = u1 * invbw, v2 = u2 * invbw, v3 = u3 * invbw;
    float meanv = ssum * invbw * (1.0f / DD);

    float L = (xmax - xmin) * invbw + 10.0f;
    float invL = __builtin_amdgcn_rcpf(L);
    // M = ceil(omega_max/(2pi) * L), omega_max = 4.4
    int M = (int)__builtin_ceilf(0.70028175f * L);
    M = M < 1 ? 1 : (M > 96 ? 96 : M);
    M = __builtin_amdgcn_readfirstlane(M);

    // v_sin/v_cos take revolutions: sin(2pi * v/L)
    v2f s1a = {__builtin_amdgcn_sinf(v0 * invL), __builtin_amdgcn_sinf(v1 * invL)};
    v2f s1b = {__builtin_amdgcn_sinf(v2 * invL), __builtin_amdgcn_sinf(v3 * invL)};
    v2f c1a = {__builtin_amdgcn_cosf(v0 * invL), __builtin_amdgcn_cosf(v1 * invL)};
    v2f c1b = {__builtin_amdgcn_cosf(v2 * invL), __builtin_amdgcn_cosf(v3 * invL)};

    v2f sma = s1a, smb = s1b, cma = c1a, cmb = c1b;   // m = 1 state
    v2f Ra = {0.f, 0.f}, Rb = {0.f, 0.f};

    // g_m = e^{-m^2 w1^2/2}: multiplicative recurrence; exp via v_exp_f32
    // (exp2) with ln->log2 constants folded: e^{a} = exp2(a*1.442695).
    float w1sq = 39.4784176044f * invL * invL;          // (2pi/L)^2
    float g   = __builtin_amdgcn_exp2f(-0.72134752f * w1sq);
    float rr  = __builtin_amdgcn_exp2f(-2.16404256f * w1sq);
    const float rho = __builtin_amdgcn_exp2f(-1.44269504f * w1sq);
    float fm = 1.0f;

    #pragma clang loop unroll_count(1)
    for (int m = 1; m <= M; ++m) {
        v2f sp = sma + smb;
        v2f cp = cma + cmb;
        float Stot = wave_sum(sp.x + sp.y);
        float Ctot = wave_sum(cp.x + cp.y);
        float sc = g * 0.31830988618f * __builtin_amdgcn_rcpf(fm); // gamma_m
        float gC = Ctot * sc, gS = Stot * sc;
        v2f vgC = {gC, gC}, vgS = {gS, gS};
        Ra = __builtin_elementwise_fma(sma, vgC, Ra);
        Ra = __builtin_elementwise_fma(cma, -vgS, Ra);
        Rb = __builtin_elementwise_fma(smb, vgC, Rb);
        Rb = __builtin_elementwise_fma(cmb, -vgS, Rb);
        // angle-addition recurrence to m+1
        v2f nsa = __builtin_elementwise_fma(sma, c1a, cma * s1a);
        v2f nca = __builtin_elementwise_fma(cma, c1a, -(sma * s1a));
        v2f nsb = __builtin_elementwise_fma(smb, c1b, cmb * s1b);
        v2f ncb = __builtin_elementwise_fma(cmb, c1b, -(smb * s1b));
        sma = nsa; cma = nca; smb = nsb; cmb = ncb;
        g *= rr; rr *= rho; fm += 1.0f;
    }

    // y = 2*cdf - 1 = 2*[(v_j - mean_v)/L + R_j/256]; PPF via Giles erfinv.
    float vv[4] = {v0, v1, v2, v3};
    float Rv[4] = {Ra.x, Ra.y, Rb.x, Rb.y};
    #pragma unroll
    for (int a = 0; a < 4; ++a) {
        float y = 2.0f * __builtin_fmaf(vv[a] - meanv, invL, Rv[a] * (1.0f / DD));
        float normed = ppf_from_y(y);
        int idx = a * 64 + lane;
        out[(size_t)row * DD + idx] = __builtin_fmaf(normed, wgt[idx], bia[idx]);
    }
}

extern "C" void kernel_launch(void* const* d_in, const int* in_sizes, int n_in,
                              void* d_out, int out_size, void* d_ws, size_t ws_size,
                              hipStream_t stream) {
    const float* x = (const float*)d_in[0];
    const float* w = (const float*)d_in[1];
    const float* b = (const float*)d_in[2];
    float* out = (float*)d_out;
    const int nrows = in_sizes[0] / DD;
    kd_layernorm_kernel<<<nrows / NW, 64 * NW, 0, stream>>>(x, w, b, out);
}

// Round 8
// 67.351 us; speedup vs baseline: 2.3903x; 1.0031x over previous
//
#include <hip/hip_runtime.h>
#include <math.h>

#define DD 256
#define NW 4     // rows (waves) per block
#define MFIX 24  // fixed mode count; with L = range_v+10, omega_24 >= 4.3 always

typedef float v2f __attribute__((ext_vector_type(2)));
typedef float v4f __attribute__((ext_vector_type(4)));

// ---- DPP wave-64 reduction helpers (no LDS, no barrier) ----
template <int CTRL>
__device__ __forceinline__ float dpp_add(float x) {
    return x + __int_as_float(__builtin_amdgcn_update_dpp(
        0, __float_as_int(x), CTRL, 0xf, 0xf, false));
}
template <int CTRL>
__device__ __forceinline__ float dpp_mov_self(float x) {
    return __int_as_float(__builtin_amdgcn_update_dpp(
        __float_as_int(x), __float_as_int(x), CTRL, 0xf, 0xf, false));
}
// After this chain lane 63 holds the 64-lane total.
__device__ __forceinline__ float wave_sum_chain(float x) {
    x = dpp_add<0x111>(x); x = dpp_add<0x112>(x);
    x = dpp_add<0x114>(x); x = dpp_add<0x118>(x);
    x = dpp_add<0x142>(x); x = dpp_add<0x143>(x);
    return x;
}
__device__ __forceinline__ float lane63(float x) {
    return __int_as_float(__builtin_amdgcn_readlane(__float_as_int(x), 63));
}
__device__ __forceinline__ float wave_max_chain(float x) {
    x = __builtin_fmaxf(x, dpp_mov_self<0x111>(x));
    x = __builtin_fmaxf(x, dpp_mov_self<0x112>(x));
    x = __builtin_fmaxf(x, dpp_mov_self<0x114>(x));
    x = __builtin_fmaxf(x, dpp_mov_self<0x118>(x));
    x = __builtin_fmaxf(x, dpp_mov_self<0x142>(x));
    x = __builtin_fmaxf(x, dpp_mov_self<0x143>(x));
    return x;
}
__device__ __forceinline__ float wave_min_chain(float x) {
    x = __builtin_fminf(x, dpp_mov_self<0x111>(x));
    x = __builtin_fminf(x, dpp_mov_self<0x112>(x));
    x = __builtin_fminf(x, dpp_mov_self<0x114>(x));
    x = __builtin_fminf(x, dpp_mov_self<0x118>(x));
    x = __builtin_fminf(x, dpp_mov_self<0x142>(x));
    x = __builtin_fminf(x, dpp_mov_self<0x143>(x));
    return x;
}

// Giles' erfinv, central branch (|y| <= 1-1/256 => w <= 4.86 < 5), branchless.
__device__ __forceinline__ float ppf_from_y(float y) {
    float omy2 = __builtin_fmaf(-y, y, 1.0f);
    float wg = __builtin_fmaf(-__builtin_amdgcn_logf(omy2), 0.69314718056f, -2.5f);
    float p = 2.81022636e-08f;
    p = __builtin_fmaf(p, wg, 3.43273939e-07f);
    p = __builtin_fmaf(p, wg, -3.5233877e-06f);
    p = __builtin_fmaf(p, wg, -4.39150654e-06f);
    p = __builtin_fmaf(p, wg, 0.00021858087f);
    p = __builtin_fmaf(p, wg, -0.00125372503f);
    p = __builtin_fmaf(p, wg, -0.00417768164f);
    p = __builtin_fmaf(p, wg, 0.246640727f);
    p = __builtin_fmaf(p, wg, 1.50140941f);
    return p * y * 1.41421356237309505f;
}

// Poisson-summation KDE-CDF (validated R6/R7), phase-split to remove the
// cross-lane reduction from the mode loop's critical path:
//   P1: sin/cos recurrence, per-lane partials PC/PS[m] (no cross-lane)
//   P2: 2*MFIX independent DPP reduction chains (latency pipelines)
//   P3: recurrence recomputed + R accumulation with wave-uniform gC/gS
// Lane l owns elements 4l..4l+3 (float4 coalesced I/O; reductions are
// lane-mapping agnostic).
__global__ __launch_bounds__(64 * NW, 4) void kd_layernorm_kernel(
        const float* __restrict__ x,
        const float* __restrict__ wgt,
        const float* __restrict__ bia,
        float* __restrict__ out) {
    const int lane = threadIdx.x & 63;
    const int wid  = threadIdx.x >> 6;
    const int row  = blockIdx.x * NW + wid;

    const v4f u = ((const v4f*)(x + (size_t)row * DD))[lane];

    float ssum = lane63(wave_sum_chain((u.x + u.y) + (u.z + u.w)));
    float qsum = lane63(wave_sum_chain(__builtin_fmaf(u.x, u.x, u.y * u.y) +
                                       __builtin_fmaf(u.z, u.z, u.w * u.w)));
    float xmax = lane63(wave_max_chain(__builtin_fmaxf(__builtin_fmaxf(u.x, u.y),
                                                       __builtin_fmaxf(u.z, u.w))));
    float xmin = lane63(wave_min_chain(__builtin_fminf(__builtin_fminf(u.x, u.y),
                                                       __builtin_fminf(u.z, u.w))));

    float var = (qsum - ssum * ssum * (1.0f / DD)) * (1.0f / (DD - 1)); // ddof=1
    float bw = 0.9f * __builtin_sqrtf(var) * 0.32987697769322355f;      // *256^-0.2
    float invbw = __builtin_amdgcn_rcpf(bw);
    v4f v = u * invbw;
    float meanv = ssum * invbw * (1.0f / DD);

    float L = (xmax - xmin) * invbw + 10.0f;   // periodization margin 10 sigma_k
    float invL = __builtin_amdgcn_rcpf(L);

    // v_sin/v_cos take revolutions; angle_1 = v/L revolutions (verified R7).
    v4f ph = v * invL;
    v4f s1, c1;
    s1.x = __builtin_amdgcn_sinf(ph.x); s1.y = __builtin_amdgcn_sinf(ph.y);
    s1.z = __builtin_amdgcn_sinf(ph.z); s1.w = __builtin_amdgcn_sinf(ph.w);
    c1.x = __builtin_amdgcn_cosf(ph.x); c1.y = __builtin_amdgcn_cosf(ph.y);
    c1.z = __builtin_amdgcn_cosf(ph.z); c1.w = __builtin_amdgcn_cosf(ph.w);

    // ---- Phase 1: recurrence + per-lane partials (issue-bound) ----
    float PC[MFIX], PS[MFIX];
    {
        v4f sm = s1, cm = c1;
        #pragma unroll
        for (int m = 0; m < MFIX; ++m) {
            PS[m] = (sm.x + sm.y) + (sm.z + sm.w);
            PC[m] = (cm.x + cm.y) + (cm.z + cm.w);
            v4f ns = __builtin_elementwise_fma(sm, c1, cm * s1);
            v4f nc = __builtin_elementwise_fma(cm, c1, -(sm * s1));
            sm = ns; cm = nc;
        }
    }

    // ---- Phase 2: 2*MFIX independent wave reductions, fold gamma_m ----
    // g_m = e^{-m^2 w1^2 / 2} via multiplicative recurrence (exp2 folded).
    {
        float w1sq = 39.4784176044f * invL * invL;  // (2pi/L)^2
        float g   = __builtin_amdgcn_exp2f(-0.72134752f * w1sq);
        float rr  = __builtin_amdgcn_exp2f(-2.16404256f * w1sq);
        const float rho = __builtin_amdgcn_exp2f(-1.44269504f * w1sq);
        #pragma unroll
        for (int m = 0; m < MFIX; ++m) {
            float Ct = lane63(wave_sum_chain(PC[m]));
            float St = lane63(wave_sum_chain(PS[m]));
            float sc = g * (0.31830988618f / (float)(m + 1)); // gamma_m, const-folded
            PC[m] = Ct * sc;   // gC_m (wave-uniform)
            PS[m] = St * sc;   // gS_m
            g *= rr; rr *= rho;
        }
    }

    // ---- Phase 3: R_j = sum_m gC_m s_mj - gS_m c_mj ----
    v4f R = {0.f, 0.f, 0.f, 0.f};
    {
        v4f sm = s1, cm = c1;
        #pragma unroll
        for (int m = 0; m < MFIX; ++m) {
            v4f vgC = {PC[m], PC[m], PC[m], PC[m]};
            v4f vgS = {PS[m], PS[m], PS[m], PS[m]};
            R = __builtin_elementwise_fma(sm, vgC, R);
            R = __builtin_elementwise_fma(cm, -vgS, R);
            v4f ns = __builtin_elementwise_fma(sm, c1, cm * s1);
            v4f nc = __builtin_elementwise_fma(cm, c1, -(sm * s1));
            sm = ns; cm = nc;
        }
    }

    // ---- Epilogue: y = 2[(v-meanv)/L + R/256] -> PPF -> scale/shift ----
    const v4f wv = ((const v4f*)wgt)[lane];
    const v4f bv = ((const v4f*)bia)[lane];
    v4f o;
    o.x = __builtin_fmaf(ppf_from_y(2.0f * __builtin_fmaf(v.x - meanv, invL, R.x * (1.0f / DD))), wv.x, bv.x);
    o.y = __builtin_fmaf(ppf_from_y(2.0f * __builtin_fmaf(v.y - meanv, invL, R.y * (1.0f / DD))), wv.y, bv.y);
    o.z = __builtin_fmaf(ppf_from_y(2.0f * __builtin_fmaf(v.z - meanv, invL, R.z * (1.0f / DD))), wv.z, bv.z);
    o.w = __builtin_fmaf(ppf_from_y(2.0f * __builtin_fmaf(v.w - meanv, invL, R.w * (1.0f / DD))), wv.w, bv.w);
    ((v4f*)(out + (size_t)row * DD))[lane] = o;
}

extern "C" void kernel_launch(void* const* d_in, const int* in_sizes, int n_in,
                              void* d_out, int out_size, void* d_ws, size_t ws_size,
                              hipStream_t stream) {
    const float* x = (const float*)d_in[0];
    const float* w = (const float*)d_in[1];
    const float* b = (const float*)d_in[2];
    float* out = (float*)d_out;
    const int nrows = in_sizes[0] / DD;
    kd_layernorm_kernel<<<nrows / NW, 64 * NW, 0, stream>>>(x, w, b, out);
}